// Round 2
// baseline (53.893 us; speedup 1.0000x reference)
//
#include <hip/hip_runtime.h>
#include <math.h>
#include <float.h>

#define BS 64          // batch
#define BLOCK 256

struct Partial {
    double s, d, pos_sum;   // online-softmax sum, weighted sum, positive prob sum
    float  m;               // running max of negative prob v
    unsigned cnt_pos, cnt_hard;
};  // 40 bytes

__device__ inline void merge_sd(float& m, double& s, double& d,
                                float m2, double s2, double d2) {
    if (s2 > 0.0) {
        if (s == 0.0) { m = m2; s = s2; d = d2; }
        else if (m2 <= m) {
            double sc = exp((double)m2 - (double)m);
            s += s2 * sc; d += d2 * sc;
        } else {
            double sc = exp((double)m - (double)m2);
            s = s * sc + s2; d = d * sc + d2; m = m2;
        }
    }
}

// numerically-stable softplus in double: log1p(exp(z)) without overflow
__device__ inline double softplus_d(double z) {
    if (z > 0.0) return z + log1p(exp(-z));
    return log1p(exp(z));
}

__global__ __launch_bounds__(BLOCK) void k1_partials(
        const float* __restrict__ inp, const int* __restrict__ lab,
        Partial* __restrict__ parts, int N, int G) {
    const int bid = blockIdx.x;
    const int b = bid / G, g = bid % G;
    const int Nc = N / G;                    // elements per block
    const int iters = Nc / (2 * BLOCK);      // 2 elements / thread / iter
    const float4* in4 = (const float4*)(inp + (size_t)b * 2u * (size_t)N);
    const int2*   lb2 = (const int2*)(lab + (size_t)b * (size_t)N);

    float m = -FLT_MAX;
    double s = 0.0, d = 0.0, psum = 0.0;
    unsigned cp = 0, ch = 0;

    const int e0base = g * Nc;
    for (int t = 0; t < iters; ++t) {
        const int e0 = e0base + t * (2 * BLOCK);       // block's 512-elem stripe
        const int idx = (e0 >> 1) + threadIdx.x;       // float4 / int2 index
        float4 f = in4[idx];                           // ch0(e),ch1(e),ch0(e+1),ch1(e+1)
        int2   l = lb2[idx];
        // element e: x = f.y, label l.x ; element e+1: x = f.w, label l.y
        #pragma unroll
        for (int k = 0; k < 2; ++k) {
            const float x  = (k == 0) ? f.y : f.w;
            const int   lb = (k == 0) ? l.x : l.y;
            const float v = expf(x);                   // prob, like reference exp(pred[:,1])
            if (lb == 1) { cp++; psum += (double)v; }
            else {
                ch += (v > 0.5f) ? 1u : 0u;
                if (v > m) {                           // online softmax rescale
                    double sc = exp((double)m - (double)v);  // exp(-huge)=0 on first hit
                    s = s * sc + 1.0;
                    d = d * sc + (double)v;
                    m = v;
                } else {
                    float w = expf(v - m);
                    s += (double)w;
                    d += (double)(v * w);
                }
            }
        }
    }

    // block tree-reduce via LDS
    __shared__ float    sm_m[BLOCK];
    __shared__ double   sm_s[BLOCK], sm_d[BLOCK], sm_p[BLOCK];
    __shared__ unsigned sm_cp[BLOCK], sm_ch[BLOCK];
    const int tid = threadIdx.x;
    sm_m[tid] = m; sm_s[tid] = s; sm_d[tid] = d; sm_p[tid] = psum;
    sm_cp[tid] = cp; sm_ch[tid] = ch;
    __syncthreads();
    for (int st = BLOCK / 2; st > 0; st >>= 1) {
        if (tid < st) {
            const int o = tid + st;
            merge_sd(m, s, d, sm_m[o], sm_s[o], sm_d[o]);
            psum += sm_p[o]; cp += sm_cp[o]; ch += sm_ch[o];
            sm_m[tid] = m; sm_s[tid] = s; sm_d[tid] = d; sm_p[tid] = psum;
            sm_cp[tid] = cp; sm_ch[tid] = ch;
        }
        __syncthreads();
    }
    if (tid == 0) {
        Partial p; p.s = s; p.d = d; p.pos_sum = psum; p.m = m;
        p.cnt_pos = cp; p.cnt_hard = ch;
        parts[bid] = p;
    }
}

__global__ __launch_bounds__(64) void k2_sample(
        const Partial* __restrict__ parts, float* __restrict__ losses,
        int* __restrict__ valids, int N, int G) {
    const int b = blockIdx.x, t = threadIdx.x;
    float m = -FLT_MAX;
    double s = 0.0, d = 0.0, p = 0.0;
    unsigned cp = 0, ch = 0;
    if (t < G) {
        Partial pp = parts[b * G + t];
        m = pp.m; s = pp.s; d = pp.d; p = pp.pos_sum; cp = pp.cnt_pos; ch = pp.cnt_hard;
    }
    for (int off = 32; off > 0; off >>= 1) {
        float    m2 = __shfl_xor(m, off);
        double   s2 = __shfl_xor(s, off);
        double   d2 = __shfl_xor(d, off);
        double   p2 = __shfl_xor(p, off);
        unsigned cp2 = __shfl_xor(cp, off);
        unsigned ch2 = __shfl_xor(ch, off);
        merge_sd(m, s, d, m2, s2, d2);
        p += p2; cp += cp2; ch += ch2;
    }
    if (t == 0) {
        const int num_pos = (int)cp;
        const double dist = (s > 0.0) ? (d / s) : 0.0;   // neg softmax distance
        double z;
        if (num_pos > 0) {
            double pos_dist = p / (double)num_pos;
            z = 4.0 * (dist - pos_dist + 0.5);
        } else {
            z = 4.0 * (dist - 1.0 + 0.5);
        }
        // stable softplus in f64: finite (~126) where f32 reference overflows to inf.
        losses[b] = (float)(softplus_d(z) * 0.25);
        valids[b] = (ch > 0) ? 1 : 0;
    }
}

__global__ __launch_bounds__(64) void k3_final(
        const float* __restrict__ losses, const int* __restrict__ valids,
        float* __restrict__ out, int B) {
    const int t = threadIdx.x;
    float l = 0.0f, v = 0.0f;
    if (t < B) {
        v = (float)valids[t];
        l = losses[t] * v;      // replicate reference losses*vf semantics
    }
    for (int off = 32; off > 0; off >>= 1) {
        l += __shfl_xor(l, off);
        v += __shfl_xor(v, off);
    }
    if (t == 0) out[0] = (v > 0.0f) ? (l / v) : 0.0f;
}

extern "C" void kernel_launch(void* const* d_in, const int* in_sizes, int n_in,
                              void* d_out, int out_size, void* d_ws, size_t ws_size,
                              hipStream_t stream) {
    const float* inp = (const float*)d_in[0];
    const int*   lab = (const int*)d_in[1];
    float* out = (float*)d_out;
    const int B = BS;
    const int N = in_sizes[1] / B;           // 262144

    int G = 64;                               // blocks per sample
    size_t need;
    for (;;) {
        need = (size_t)B * G * sizeof(Partial) + (size_t)B * (sizeof(float) + sizeof(int));
        if (need <= ws_size || G == 1) break;
        G >>= 1;
    }
    Partial* parts = (Partial*)d_ws;
    float* losses = (float*)((char*)d_ws + (size_t)B * G * sizeof(Partial));
    int*   valids = (int*)(losses + B);

    k1_partials<<<B * G, BLOCK, 0, stream>>>(inp, lab, parts, N, G);
    k2_sample<<<B, 64, 0, stream>>>(parts, losses, valids, N, G);
    k3_final<<<1, 64, 0, stream>>>(losses, valids, out, B);
}

// Round 3
// 39.008 us; speedup vs baseline: 1.3816x; 1.3816x over previous
//
#include <hip/hip_runtime.h>
#include <math.h>
#include <float.h>

#define BLOCK 256
#define GPS 32          // blocks per sample
#define BS 64           // batch

struct Partial { double s, d, p; unsigned cp, ch; };   // 32 B

// exp(v) for v >= 0 (v up to ~700) without libm f64 exp:
// exp(v) = 2^(v*log2e) = exp2f(frac) * 2^n, 2^n built via f64 exponent bits.
__device__ inline double exp_pos_d(float v) {
    float t = v * 1.44269504f;          // v*log2(e)
    float nf = rintf(t);
    float r = t - nf;                    // [-0.5, 0.5]
    float p = exp2f(r);                  // one v_exp_f32
    int n = (int)nf;
    n = n > 1020 ? 1020 : n;             // safety: keep exponent field valid
    double scale = __longlong_as_double(((long long)(n + 1023)) << 52);
    return (double)p * scale;
}

__global__ __launch_bounds__(BLOCK) void k1_partials(
        const float* __restrict__ inp, const int* __restrict__ lab,
        Partial* __restrict__ parts, int N, int G) {
    const int bid = blockIdx.x;
    const int b = bid / G, g = bid % G;
    const int Nc = N / G;                     // elements per block
    const int tid = threadIdx.x;
    const float4* in4 = (const float4*)(inp + (size_t)b * 2u * (size_t)N);
    const int2*   lb2 = (const int2*)(lab + (size_t)b * (size_t)N);
    const int slotBase = (g * Nc) >> 1;       // float4/int2 slot of stripe start
    const int iters = Nc / (4 * BLOCK);       // 4 elements / thread / iter

    double S = 0.0, D = 0.0;
    float psum = 0.0f;
    unsigned cp = 0, ch = 0;

    for (int it = 0; it < iters; ++it) {
        const int s0 = slotBase + it * (2 * BLOCK) + tid;
        float4 f0 = in4[s0];
        float4 f1 = in4[s0 + BLOCK];
        int2   l0 = lb2[s0];
        int2   l1 = lb2[s0 + BLOCK];
        const float xs[4] = { f0.y, f0.w, f1.y, f1.w };
        const int   ls[4] = { l0.x, l0.y, l1.x, l1.y };
        #pragma unroll
        for (int k = 0; k < 4; ++k) {
            const float x = xs[k];
            const bool pos = (ls[k] != 0);
            const float v = __expf(x);                        // prob
            cp   += pos ? 1u : 0u;
            psum += pos ? v : 0.0f;
            ch   |= (!pos && x > -0.69314718f) ? 1u : 0u;     // v>0.5 <=> x>ln(0.5)
            const double w = pos ? 0.0 : exp_pos_d(v);        // softmax weight (unnormalized)
            S += w;
            D += (double)v * w;
        }
    }

    // wave64 butterfly reduce (plain adds — no exp, no branches)
    double P = (double)psum;
    #pragma unroll
    for (int off = 32; off > 0; off >>= 1) {
        S  += __shfl_xor(S, off);
        D  += __shfl_xor(D, off);
        P  += __shfl_xor(P, off);
        cp += __shfl_xor(cp, off);
        ch |= __shfl_xor(ch, off);
    }

    __shared__ Partial sw[BLOCK / 64];
    const int wid = tid >> 6, lane = tid & 63;
    if (lane == 0) { sw[wid].s = S; sw[wid].d = D; sw[wid].p = P; sw[wid].cp = cp; sw[wid].ch = ch; }
    __syncthreads();
    if (tid == 0) {
        for (int wv = 1; wv < BLOCK / 64; ++wv) {
            S += sw[wv].s; D += sw[wv].d; P += sw[wv].p; cp += sw[wv].cp; ch |= sw[wv].ch;
        }
        Partial o; o.s = S; o.d = D; o.p = P; o.cp = cp; o.ch = ch;
        parts[bid] = o;
    }
}

// Fused per-sample loss + batch mean: one block of 1024 threads.
// 2048 partials -> 2/thread -> 16 threads per sample (segmented shfl reduce).
__global__ __launch_bounds__(1024) void k2_final(
        const Partial* __restrict__ parts, float* __restrict__ out) {
    const int tid = threadIdx.x;              // 0..1023
    Partial a = parts[2 * tid];
    Partial c = parts[2 * tid + 1];
    double S = a.s + c.s, D = a.d + c.d, P = a.p + c.p;
    unsigned cp = a.cp + c.cp, ch = a.ch | c.ch;

    #pragma unroll
    for (int off = 8; off > 0; off >>= 1) {   // reduce within 16-lane segments
        S  += __shfl_xor(S, off);
        D  += __shfl_xor(D, off);
        P  += __shfl_xor(P, off);
        cp += __shfl_xor(cp, off);
        ch |= __shfl_xor(ch, off);
    }

    __shared__ float    sl[BS];
    __shared__ unsigned sv[BS];
    const int sample = tid >> 4;
    if ((tid & 15) == 0) {
        const double dist = (S > 0.0) ? (D / S) : 0.0;   // neg softmax distance
        double z;
        if (cp > 0) z = 4.0 * (dist - P / (double)cp + 0.5);
        else        z = 4.0 * (dist - 0.5);
        // stable softplus in f64 (finite where f32 ref overflows to inf)
        const double sp = (z > 0.0) ? z + log1p(exp(-z)) : log1p(exp(z));
        sl[sample] = (float)(sp * 0.25);
        sv[sample] = (ch > 0) ? 1u : 0u;
    }
    __syncthreads();
    if (tid < 64) {
        float vv = (float)sv[tid];
        float l  = sl[tid] * vv;
        #pragma unroll
        for (int off = 32; off > 0; off >>= 1) {
            l  += __shfl_xor(l, off);
            vv += __shfl_xor(vv, off);
        }
        if (tid == 0) out[0] = (vv > 0.0f) ? (l / vv) : 0.0f;
    }
}

extern "C" void kernel_launch(void* const* d_in, const int* in_sizes, int n_in,
                              void* d_out, int out_size, void* d_ws, size_t ws_size,
                              hipStream_t stream) {
    const float* inp = (const float*)d_in[0];
    const int*   lab = (const int*)d_in[1];
    float* out = (float*)d_out;
    const int B = BS;
    const int N = in_sizes[1] / B;            // 262144

    Partial* parts = (Partial*)d_ws;          // 2048 * 32 B = 64 KiB

    k1_partials<<<B * GPS, BLOCK, 0, stream>>>(inp, lab, parts, N, GPS);
    k2_final<<<1, 1024, 0, stream>>>(parts, out);
}